// Round 1
// baseline (327.772 us; speedup 1.0000x reference)
//
#include <hip/hip_runtime.h>
#include <math.h>

#define N_NODES 50000
#define E_ORIG  500000
#define E_TOT   550000
#define NB      196   // scan blocks: 196*256 = 50176 >= N_NODES

typedef _Float16 half8 __attribute__((ext_vector_type(8)));
typedef _Float16 half4 __attribute__((ext_vector_type(4)));
typedef float    v4f   __attribute__((ext_vector_type(4)));

// ------------------------------------------------------------------
// Fused prep: W1/W2 transpose+cast, vs2/vd2 = W2 @ a2, edge degree
// count (deg pre-zeroed by hipMemsetAsync).
// ------------------------------------------------------------------
__global__ void k_prepw(const float* __restrict__ W1, const float* __restrict__ W2,
                        const float* __restrict__ as2, const float* __restrict__ ad2,
                        const int* __restrict__ ei,
                        _Float16* __restrict__ w1t, _Float16* __restrict__ w2t,
                        float* __restrict__ vs2, float* __restrict__ vd2,
                        int* __restrict__ deg) {
    int i = blockIdx.x * blockDim.x + threadIdx.x;
    if (i < E_TOT) {
        int d = (i < E_ORIG) ? ei[E_ORIG + i] : (i - E_ORIG);
        atomicAdd(&deg[d], 1);
        return;
    }
    int j = i - E_TOT;
    if (j < 128 * 256) {
        int k = j >> 8, c = j & 255;
        w1t[(size_t)c * 128 + k] = (_Float16)W1[j];
        return;
    }
    j -= 128 * 256;
    if (j < 256 * 256) {
        int k = j >> 8, c = j & 255;
        w2t[(size_t)c * 256 + k] = (_Float16)W2[j];
        return;
    }
    j -= 256 * 256;
    if (j < 256) {
        float s = 0.f, d = 0.f;
        for (int c = 0; c < 256; c++) {
            float w = W2[(size_t)j * 256 + c];
            s += w * as2[c];
            d += w * ad2[c];
        }
        vs2[j] = s;
        vd2[j] = d;
    }
}

// ------------------------------------------------------------------
// CSR scan + scatter
// ------------------------------------------------------------------
__global__ __launch_bounds__(256) void k_blocksum(const int* __restrict__ deg,
                                                  int* __restrict__ bsum) {
    int t = threadIdx.x;
    int i = blockIdx.x * 256 + t;
    int v = (i < N_NODES) ? deg[i] : 0;
#pragma unroll
    for (int mk = 1; mk < 64; mk <<= 1) v += __shfl_xor(v, mk, 64);
    __shared__ int ws[4];
    if ((t & 63) == 0) ws[t >> 6] = v;
    __syncthreads();
    if (t == 0) bsum[blockIdx.x] = ws[0] + ws[1] + ws[2] + ws[3];
}

__global__ __launch_bounds__(256) void k_scanbsum(const int* __restrict__ bsum,
                                                  int* __restrict__ boff) {
    __shared__ int s[256];
    int t = threadIdx.x;
    int v = (t < NB) ? bsum[t] : 0;
    s[t] = v;
    __syncthreads();
    for (int o = 1; o < 256; o <<= 1) {
        int x = (t >= o) ? s[t - o] : 0;
        __syncthreads();
        s[t] += x;
        __syncthreads();
    }
    if (t <= NB) boff[t] = (t == 0) ? 0 : s[t - 1];
}

__global__ __launch_bounds__(256) void k_offsets(const int* __restrict__ deg,
                                                 const int* __restrict__ boff,
                                                 int* __restrict__ offsets,
                                                 int* __restrict__ cur) {
    __shared__ int s[256];
    int t = threadIdx.x;
    int i = blockIdx.x * 256 + t;
    int v = (i < N_NODES) ? deg[i] : 0;
    s[t] = v;
    __syncthreads();
    for (int o = 1; o < 256; o <<= 1) {
        int x = (t >= o) ? s[t - o] : 0;
        __syncthreads();
        s[t] += x;
        __syncthreads();
    }
    int off = boff[blockIdx.x] + s[t] - v;  // exclusive
    if (i <= N_NODES) {
        offsets[i] = off;
        if (i < N_NODES) cur[i] = off;
    }
}

__global__ void k_scatter(const int* __restrict__ ei, int* __restrict__ cur,
                          int* __restrict__ csr_src) {
    int e = blockIdx.x * blockDim.x + threadIdx.x;
    if (e >= E_TOT) return;
    int s, d;
    if (e < E_ORIG) { s = ei[e]; d = ei[E_ORIG + e]; }
    else            { s = e - E_ORIG; d = s; }
    int slot = atomicAdd(&cur[d], 1);
    csr_src[slot] = s;
}

// ------------------------------------------------------------------
// GEMM1: H[N,256] = cvt16(X[N,128]) @ w1t^T + fused es/ed.
// 32-row tile; 2-pass LDS epilogue (8.4 KB).
// ------------------------------------------------------------------
__global__ __launch_bounds__(256) void k_gemm1(
    const float* __restrict__ X, const _Float16* __restrict__ Bt,
    const float* __restrict__ a_s, const float* __restrict__ a_d,
    _Float16* __restrict__ H, float* __restrict__ es, float* __restrict__ ed) {
    int t = threadIdx.x, w = t >> 6, lane = t & 63;
    int quad = lane >> 4, l16 = lane & 15;
    int row0 = blockIdx.x * 32;
    int colbase = w * 64;

    v4f acc[2][4];
#pragma unroll
    for (int i = 0; i < 2; i++)
#pragma unroll
        for (int j = 0; j < 4; j++) acc[i][j] = (v4f){0.f, 0.f, 0.f, 0.f};

    int r0 = row0 + l16;      if (r0 >= N_NODES) r0 = N_NODES - 1;
    int r1 = row0 + 16 + l16; if (r1 >= N_NODES) r1 = N_NODES - 1;
    const float4* a0p = (const float4*)(X + (size_t)r0 * 128) + quad * 2;
    const float4* a1p = (const float4*)(X + (size_t)r1 * 128) + quad * 2;
    const half8* bp[4];
#pragma unroll
    for (int ct = 0; ct < 4; ct++)
        bp[ct] = (const half8*)(Bt + (size_t)(colbase + ct * 16 + l16) * 128 + quad * 8);

#pragma unroll
    for (int kc = 0; kc < 4; kc++) {
        float4 f0 = a0p[kc * 8], f1 = a0p[kc * 8 + 1];
        float4 f2 = a1p[kc * 8], f3 = a1p[kc * 8 + 1];
        half8 av0 = (half8){(_Float16)f0.x, (_Float16)f0.y, (_Float16)f0.z, (_Float16)f0.w,
                            (_Float16)f1.x, (_Float16)f1.y, (_Float16)f1.z, (_Float16)f1.w};
        half8 av1 = (half8){(_Float16)f2.x, (_Float16)f2.y, (_Float16)f2.z, (_Float16)f2.w,
                            (_Float16)f3.x, (_Float16)f3.y, (_Float16)f3.z, (_Float16)f3.w};
#pragma unroll
        for (int ct = 0; ct < 4; ct++) {
            half8 bv = bp[ct][kc * 4];
            acc[0][ct] = __builtin_amdgcn_mfma_f32_16x16x32_f16(av0, bv, acc[0][ct], 0, 0, 0);
            acc[1][ct] = __builtin_amdgcn_mfma_f32_16x16x32_f16(av1, bv, acc[1][ct], 0, 0, 0);
        }
    }

    float asv[4], adv[4];
#pragma unroll
    for (int ct = 0; ct < 4; ct++) {
        asv[ct] = a_s[colbase + ct * 16 + l16];
        adv[ct] = a_d[colbase + ct * 16 + l16];
    }
#pragma unroll
    for (int rt = 0; rt < 2; rt++) {
#pragma unroll
        for (int hp = 0; hp < 2; hp++) {
#pragma unroll
            for (int reg = 0; reg < 4; reg++) {
                float ps = acc[rt][2 * hp][reg] * asv[2 * hp] +
                           acc[rt][2 * hp + 1][reg] * asv[2 * hp + 1];
                float pd = acc[rt][2 * hp][reg] * adv[2 * hp] +
                           acc[rt][2 * hp + 1][reg] * adv[2 * hp + 1];
#pragma unroll
                for (int mk = 1; mk < 16; mk <<= 1) {
                    ps += __shfl_xor(ps, mk, 64);
                    pd += __shfl_xor(pd, mk, 64);
                }
                if (l16 == 0) {
                    int row = row0 + rt * 16 + quad * 4 + reg;
                    if (row < N_NODES) {
                        int head = w * 2 + hp;
                        es[(size_t)row * 8 + head] = ps;
                        ed[(size_t)row * 8 + head] = pd;
                    }
                }
            }
        }
    }

    // 2-pass LDS-staged f16 store (16 rows per pass)
    __shared__ _Float16 SH[16][264];
#pragma unroll
    for (int rt = 0; rt < 2; rt++) {
        if (rt) __syncthreads();
#pragma unroll
        for (int ct = 0; ct < 4; ct++)
#pragma unroll
            for (int reg = 0; reg < 4; reg++)
                SH[quad * 4 + reg][colbase + ct * 16 + l16] = (_Float16)acc[rt][ct][reg];
        __syncthreads();
#pragma unroll
        for (int j = 0; j < 2; j++) {
            int c = j * 256 + t;
            int row = c >> 5, col8 = c & 31;
            int gr = row0 + rt * 16 + row;
            if (gr < N_NODES)
                *(half8*)(H + (size_t)gr * 256 + col8 * 8) = *(const half8*)&SH[row][col8 * 8];
        }
    }
}

// ------------------------------------------------------------------
// GEMM2: OUT[N,256] = A[N,256] @ w2t^T + bias, f32 out.
// 32-row tile; 2-pass LDS epilogue (16.6 KB).
// ------------------------------------------------------------------
__global__ __launch_bounds__(256) void k_gemm2(
    const _Float16* __restrict__ A, const _Float16* __restrict__ Bt,
    const float* __restrict__ bias, float* __restrict__ OUT) {
    int t = threadIdx.x, w = t >> 6, lane = t & 63;
    int quad = lane >> 4, l16 = lane & 15;
    int row0 = blockIdx.x * 32;
    int colbase = w * 64;

    v4f acc[2][4];
#pragma unroll
    for (int i = 0; i < 2; i++)
#pragma unroll
        for (int j = 0; j < 4; j++) acc[i][j] = (v4f){0.f, 0.f, 0.f, 0.f};

    int r0 = row0 + l16;      if (r0 >= N_NODES) r0 = N_NODES - 1;
    int r1 = row0 + 16 + l16; if (r1 >= N_NODES) r1 = N_NODES - 1;
    const half8* a0 = (const half8*)(A + (size_t)r0 * 256 + quad * 8);
    const half8* a1 = (const half8*)(A + (size_t)r1 * 256 + quad * 8);
    const half8* bp[4];
#pragma unroll
    for (int ct = 0; ct < 4; ct++)
        bp[ct] = (const half8*)(Bt + (size_t)(colbase + ct * 16 + l16) * 256 + quad * 8);

#pragma unroll
    for (int kc = 0; kc < 8; kc++) {
        half8 av0 = a0[kc * 4];
        half8 av1 = a1[kc * 4];
#pragma unroll
        for (int ct = 0; ct < 4; ct++) {
            half8 bv = bp[ct][kc * 4];
            acc[0][ct] = __builtin_amdgcn_mfma_f32_16x16x32_f16(av0, bv, acc[0][ct], 0, 0, 0);
            acc[1][ct] = __builtin_amdgcn_mfma_f32_16x16x32_f16(av1, bv, acc[1][ct], 0, 0, 0);
        }
    }

    __shared__ float SF[16][260];
#pragma unroll
    for (int rt = 0; rt < 2; rt++) {
        if (rt) __syncthreads();
#pragma unroll
        for (int ct = 0; ct < 4; ct++)
#pragma unroll
            for (int reg = 0; reg < 4; reg++)
                SF[quad * 4 + reg][colbase + ct * 16 + l16] = acc[rt][ct][reg];
        __syncthreads();
#pragma unroll
        for (int j = 0; j < 4; j++) {
            int c = j * 256 + t;
            int row = c >> 6, c4 = c & 63;
            int gr = row0 + rt * 16 + row;
            if (gr < N_NODES) {
                float4 v = *(const float4*)&SF[row][c4 * 4];
                float4 bb = ((const float4*)bias)[c4];
                float4 o = make_float4(v.x + bb.x, v.y + bb.y, v.z + bb.z, v.w + bb.w);
                *(float4*)(OUT + (size_t)gr * 256 + c4 * 4) = o;
            }
        }
    }
}

// ------------------------------------------------------------------
// Layer-1 aggregation, R8 restructure:
//   phase 1 (lane-parallel): lane l computes all-8-head softmax
//     weights for edge beg+l -> conflict-free LDS WT[4][8][68]
//   phase 2: per-edge loop with SGPR row base (readlane) ->
//     saddr-form half4 gather; 8-unroll + uniform (4,2,1) tail.
// Removes per-edge exp/leaky/es-load/bpermute from the inner loop.
// ------------------------------------------------------------------
#define EDGE1(I) {                                                         \
    unsigned su = (unsigned)__builtin_amdgcn_readlane(sreg, (I));          \
    float wb = wrow[(I)];                                                  \
    half4 hv = *((const half4*)((const char*)H1 + ((size_t)su << 9)) + lane); \
    a0 += wb * (float)hv[0]; a1 += wb * (float)hv[1];                      \
    a2 += wb * (float)hv[2]; a3 += wb * (float)hv[3];                      \
    den += wb; }

__global__ __launch_bounds__(256) void k_agg1(
    const _Float16* __restrict__ H1, const float* __restrict__ es,
    const float* __restrict__ ed, const int* __restrict__ offsets,
    const int* __restrict__ csr_src, const float* __restrict__ b1,
    const float* __restrict__ vs2, const float* __restrict__ vd2,
    _Float16* __restrict__ out1, float* __restrict__ es2,
    float* __restrict__ ed2) {
    int t = threadIdx.x, w = t >> 6, lane = t & 63;
    int n = blockIdx.x * 4 + w;  // 12500 x 4 waves = 50000
    int hB = lane >> 3;          // head of this lane's 4 channels
    int beg = offsets[n];
    int deg = offsets[n + 1] - beg;

    // dst logits for all 8 heads (wave-uniform)
    float edv[8];
    {
        const float4* edp = (const float4*)(ed + (size_t)n * 8);
        float4 d0 = edp[0], d1 = edp[1];
        edv[0] = d0.x; edv[1] = d0.y; edv[2] = d0.z; edv[3] = d0.w;
        edv[4] = d1.x; edv[5] = d1.y; edv[6] = d1.z; edv[7] = d1.w;
    }

    // WT[w][h][i]: weight of edge i, head h. Pad 68 -> read banks (4h+i)%32,
    // conflict-free 8-way broadcast; writes are stride-1 (2-way = free).
    __shared__ float WT[4][8][68];
    float* wrow = &WT[w][hB][0];

    float a0 = 0.f, a1 = 0.f, a2 = 0.f, a3 = 0.f, den = 0.f;

    for (int base = 0; base < deg; base += 64) {
        int rem = deg - base; if (rem > 64) rem = 64;
        int idx = beg + base + lane;
        if (idx >= E_TOT) idx = E_TOT - 1;
        int sreg = csr_src[idx];

        // ---- phase 1: this lane's edge -> 8 head weights in LDS ----
        {
            const float4* ep = (const float4*)(es + ((size_t)(unsigned)sreg << 3));
            float4 e0 = ep[0], e1 = ep[1];
            float l0 = e0.x + edv[0], l1 = e0.y + edv[1];
            float l2 = e0.z + edv[2], l3 = e0.w + edv[3];
            float l4 = e1.x + edv[4], l5 = e1.y + edv[5];
            float l6 = e1.z + edv[6], l7 = e1.w + edv[7];
            l0 = fmaxf(l0, 0.2f * l0); l1 = fmaxf(l1, 0.2f * l1);
            l2 = fmaxf(l2, 0.2f * l2); l3 = fmaxf(l3, 0.2f * l3);
            l4 = fmaxf(l4, 0.2f * l4); l5 = fmaxf(l5, 0.2f * l5);
            l6 = fmaxf(l6, 0.2f * l6); l7 = fmaxf(l7, 0.2f * l7);
            WT[w][0][lane] = __expf(l0); WT[w][1][lane] = __expf(l1);
            WT[w][2][lane] = __expf(l2); WT[w][3][lane] = __expf(l3);
            WT[w][4][lane] = __expf(l4); WT[w][5][lane] = __expf(l5);
            WT[w][6][lane] = __expf(l6); WT[w][7][lane] = __expf(l7);
        }
        // wave-local LDS handoff (no cross-wave sharing -> no barrier)
        asm volatile("s_waitcnt lgkmcnt(0)" ::: "memory");

        // ---- phase 2: gather + accumulate ----
        int i = 0, nf = rem & ~7;
        for (; i < nf; i += 8) {
            EDGE1(i);     EDGE1(i + 1); EDGE1(i + 2); EDGE1(i + 3);
            EDGE1(i + 4); EDGE1(i + 5); EDGE1(i + 6); EDGE1(i + 7);
        }
        if (rem & 4) { EDGE1(i); EDGE1(i + 1); EDGE1(i + 2); EDGE1(i + 3); i += 4; }
        if (rem & 2) { EDGE1(i); EDGE1(i + 1); i += 2; }
        if (rem & 1) { EDGE1(i); }
    }

    float r = 1.f / (den + 1e-16f);
    float4 bb = ((const float4*)b1)[lane];
    float o0 = a0 * r + bb.x, o1 = a1 * r + bb.y;
    float o2 = a2 * r + bb.z, o3 = a3 * r + bb.w;
    o0 = o0 > 0.f ? o0 : __expf(o0) - 1.f;
    o1 = o1 > 0.f ? o1 : __expf(o1) - 1.f;
    o2 = o2 > 0.f ? o2 : __expf(o2) - 1.f;
    o3 = o3 > 0.f ? o3 : __expf(o3) - 1.f;
    ((half4*)(out1 + (size_t)n * 256))[lane] =
        (half4){(_Float16)o0, (_Float16)o1, (_Float16)o2, (_Float16)o3};

    // fused layer-2 attention coefficients
    float4 vs = ((const float4*)vs2)[lane];
    float4 vd = ((const float4*)vd2)[lane];
    float ps = o0 * vs.x + o1 * vs.y + o2 * vs.z + o3 * vs.w;
    float pd = o0 * vd.x + o1 * vd.y + o2 * vd.z + o3 * vd.w;
#pragma unroll
    for (int mk = 1; mk < 64; mk <<= 1) {
        ps += __shfl_xor(ps, mk, 64);
        pd += __shfl_xor(pd, mk, 64);
    }
    if (lane == 0) { es2[n] = ps; ed2[n] = pd; }
}

// ------------------------------------------------------------------
// Layer-2 aggregation, R8 restructure: single head -> weights stay
// in registers, broadcast via readlane (no LDS). Same saddr gather.
// ------------------------------------------------------------------
#define EDGE2(I) {                                                         \
    unsigned su = (unsigned)__builtin_amdgcn_readlane(sreg, (I));          \
    float wb = __int_as_float(__builtin_amdgcn_readlane(wbits, (I)));      \
    half4 hv = *((const half4*)((const char*)O1 + ((size_t)su << 9)) + lane); \
    a0 += wb * (float)hv[0]; a1 += wb * (float)hv[1];                      \
    a2 += wb * (float)hv[2]; a3 += wb * (float)hv[3];                      \
    den += wb; }

__global__ __launch_bounds__(256) void k_agg2(
    const _Float16* __restrict__ O1, const float* __restrict__ es2,
    const float* __restrict__ ed2, const int* __restrict__ offsets,
    const int* __restrict__ csr_src, _Float16* __restrict__ xagg) {
    int t = threadIdx.x, w = t >> 6, lane = t & 63;
    int n = blockIdx.x * 4 + w;
    int beg = offsets[n];
    int deg = offsets[n + 1] - beg;
    float edn = ed2[n];

    float a0 = 0.f, a1 = 0.f, a2 = 0.f, a3 = 0.f, den = 0.f;

    for (int base = 0; base < deg; base += 64) {
        int rem = deg - base; if (rem > 64) rem = 64;
        int idx = beg + base + lane;
        if (idx >= E_TOT) idx = E_TOT - 1;
        int sreg = csr_src[idx];

        // ---- phase 1: lane-parallel weight for this lane's edge ----
        float l = es2[sreg] + edn;
        l = fmaxf(l, 0.2f * l);
        int wbits = __float_as_int(__expf(l));

        // ---- phase 2 ----
        int i = 0, nf = rem & ~7;
        for (; i < nf; i += 8) {
            EDGE2(i);     EDGE2(i + 1); EDGE2(i + 2); EDGE2(i + 3);
            EDGE2(i + 4); EDGE2(i + 5); EDGE2(i + 6); EDGE2(i + 7);
        }
        if (rem & 4) { EDGE2(i); EDGE2(i + 1); EDGE2(i + 2); EDGE2(i + 3); i += 4; }
        if (rem & 2) { EDGE2(i); EDGE2(i + 1); i += 2; }
        if (rem & 1) { EDGE2(i); }
    }

    float r = 1.f / (den + 1e-16f);
    ((half4*)(xagg + (size_t)n * 256))[lane] =
        (half4){(_Float16)(a0 * r), (_Float16)(a1 * r),
                (_Float16)(a2 * r), (_Float16)(a3 * r)};
}

// ------------------------------------------------------------------
extern "C" void kernel_launch(void* const* d_in, const int* in_sizes, int n_in,
                              void* d_out, int out_size, void* d_ws, size_t ws_size,
                              hipStream_t stream) {
    const float* x   = (const float*)d_in[0];
    const int*   ei  = (const int*)d_in[1];
    const float* W1  = (const float*)d_in[2];
    const float* as1 = (const float*)d_in[3];
    const float* ad1 = (const float*)d_in[4];
    const float* b1  = (const float*)d_in[5];
    const float* W2  = (const float*)d_in[6];
    const float* as2 = (const float*)d_in[7];
    const float* ad2 = (const float*)d_in[8];
    const float* b2  = (const float*)d_in[9];
    float* out = (float*)d_out;

    char* ws = (char*)d_ws;
    size_t off = 0;
    auto alloc = [&](size_t bytes) {
        void* p = ws + off;
        off = (off + bytes + 255) & ~(size_t)255;
        return p;
    };
    _Float16* h1h     = (_Float16*)alloc((size_t)N_NODES * 256 * 2);
    _Float16* out1h   = (_Float16*)alloc((size_t)N_NODES * 256 * 2);
    _Float16* xagg    = (_Float16*)alloc((size_t)N_NODES * 256 * 2);
    _Float16* w1t     = (_Float16*)alloc((size_t)128 * 256 * 2);
    _Float16* w2t     = (_Float16*)alloc((size_t)256 * 256 * 2);
    float*    es1     = (float*)alloc((size_t)N_NODES * 8 * 4);
    float*    ed1     = (float*)alloc((size_t)N_NODES * 8 * 4);
    float*    es2     = (float*)alloc((size_t)N_NODES * 4);
    float*    ed2     = (float*)alloc((size_t)N_NODES * 4);
    float*    vs2     = (float*)alloc(256 * 4);
    float*    vd2     = (float*)alloc(256 * 4);
    int*      deg     = (int*)alloc((size_t)N_NODES * 4);
    int*      offsets = (int*)alloc((size_t)(N_NODES + 1) * 4);
    int*      cur     = (int*)alloc((size_t)N_NODES * 4);
    int*      csr_src = (int*)alloc((size_t)E_TOT * 4);
    int*      bsum    = (int*)alloc((size_t)NB * 4);
    int*      boff    = (int*)alloc((size_t)(NB + 1) * 4);

    const int TB = 256;
    int gridE = (E_TOT + TB - 1) / TB;
    int gridG = (N_NODES + 31) / 32;   // 32-row GEMM tiles
    int gridA = N_NODES / 4;           // wave-per-node

    // CSR build (deg zeroed by memset; count fused into prepw)
    hipMemsetAsync(deg, 0, (size_t)N_NODES * 4, stream);
    int prepN = E_TOT + 128 * 256 + 256 * 256 + 256;
    k_prepw<<<(prepN + TB - 1) / TB, TB, 0, stream>>>(W1, W2, as2, ad2, ei,
                                                      w1t, w2t, vs2, vd2, deg);
    k_blocksum<<<NB, TB, 0, stream>>>(deg, bsum);
    k_scanbsum<<<1, TB, 0, stream>>>(bsum, boff);
    k_offsets<<<NB, TB, 0, stream>>>(deg, boff, offsets, cur);
    k_scatter<<<gridE, TB, 0, stream>>>(ei, cur, csr_src);

    // layer 1
    k_gemm1<<<gridG, TB, 0, stream>>>(x, w1t, as1, ad1, h1h, es1, ed1);
    k_agg1<<<gridA, TB, 0, stream>>>(h1h, es1, ed1, offsets, csr_src, b1,
                                     vs2, vd2, out1h, es2, ed2);

    // layer 2: aggregate first (linearity), then GEMM straight to d_out
    k_agg2<<<gridA, TB, 0, stream>>>(out1h, es2, ed2, offsets, csr_src, xagg);
    k_gemm2<<<gridG, TB, 0, stream>>>(xagg, w2t, b2, out);
}